// Round 10
// baseline (415.375 us; speedup 1.0000x reference)
//
#include <hip/hip_runtime.h>
#include <stdint.h>

#define O_DIM 2048
#define I_DIM 4096
#define BS_TOK 8192   // 4*2048 tokens
#define KCB 256
#define PQD 8

typedef __attribute__((ext_vector_type(8))) __bf16 bf16x8;
typedef __attribute__((ext_vector_type(4))) float f32x4;
typedef __attribute__((ext_vector_type(8))) unsigned short us8;

static __device__ __forceinline__ unsigned short f32_to_bf16(float f) {
    unsigned int u = __float_as_uint(f);
    u += 0x7fffu + ((u >> 16) & 1u);   // round-to-nearest-even
    return (unsigned short)(u >> 16);
}

static __device__ __forceinline__ float bf16_to_f32(unsigned short u) {
    return __uint_as_float((unsigned int)u << 16);
}

static __device__ __forceinline__ unsigned int pack2(unsigned short lo, unsigned short hi) {
    return (unsigned int)lo | ((unsigned int)hi << 16);
}

// ---------------- 1. MFMA-based rowscale+assignment, fused with x->bf16 convert ----------------
// r9 counters: dur pinned 147-152us across 5 configs, VALUBusy 60%, MfmaUtil 0
// -> the 8-deep fmaf dot chains ARE the cost. Move them to the matrix pipe:
// e[cw][grp] = mfma([-2c | n2] , [w | s]) with split-bf16 (hi+lo, 4 terms) for
// ~fp32-level error. TAU widened 1.5e-4 -> 2.5e-4 (CUT 3e-4 -> 5e-4); the fp64
// exact fallback (unchanged) still resolves all borderline slots, so argmin
// semantics are preserved. Layouts match the verified GEMM fragment mappings.
#define TAU 2.5e-4f
#define CUT 5.0e-4f

// A-frag LDS: [nt 0..15][term 0..1][kq 0..1][lq 0..15] -> 8 ushorts (16B)
#define AOFF(nt, term, kq, lq) ((((((nt) * 2 + (term)) * 2 + (kq)) * 16 + (lq))) * 8)
#define ZOFF 8192   // 16B zero slice for k-quads 2,3

__global__ __launch_bounds__(256) void assign_convert_kernel(const float* __restrict__ weight,
                                                             const float* __restrict__ codebook,
                                                             unsigned short* __restrict__ wq,
                                                             const float* __restrict__ x,
                                                             unsigned short* __restrict__ xb) {
    __shared__ __align__(16) float cb[KCB * PQD];       // 8 KB (fp32, for fallback + dequant)
    __shared__ float n2[KCB];                           // 1 KB
    __shared__ float red[4];
    __shared__ __align__(16) unsigned short aLds[ZOFF + 8];  // 16 KB + zero slice

    const int bid = blockIdx.x;
    const int t = threadIdx.x;

    if ((bid % 3) == 2) {
        // ---- convert role: 1024 blocks x 32K contiguous elems each ----
        const size_t base = (size_t)(bid / 3) * 32768 + (size_t)t * 8;
#pragma unroll 4
        for (int it = 0; it < 16; ++it) {
            size_t i = base + (size_t)it * 2048;
            float4 v0 = *(const float4*)(x + i);
            float4 v1 = *(const float4*)(x + i + 4);
            uint4 r;
            r.x = pack2(f32_to_bf16(v0.x), f32_to_bf16(v0.y));
            r.y = pack2(f32_to_bf16(v0.z), f32_to_bf16(v0.w));
            r.z = pack2(f32_to_bf16(v1.x), f32_to_bf16(v1.y));
            r.w = pack2(f32_to_bf16(v1.z), f32_to_bf16(v1.w));
            *(uint4*)(xb + i) = r;
        }
        return;
    }

    // ---- assign role: one output row per block, MFMA distance search ----
    const int o = (bid / 3) * 2 + (bid % 3);   // row 0..2047
    const int lane = t & 63;
    const int wv = t >> 6;
    const int quad = lane >> 4;
    const int lq = lane & 15;

    // --- stage codebook (thread t <-> codeword t): cb fp32, n2, A-fragments ---
    float4 c0 = *(const float4*)(codebook + t * PQD);
    float4 c1 = *(const float4*)(codebook + t * PQD + 4);
    *(float4*)&cb[t * PQD]     = c0;
    *(float4*)&cb[t * PQD + 4] = c1;
    double n2d = 0.0;
    n2d = fma((double)c0.x, (double)c0.x, n2d); n2d = fma((double)c0.y, (double)c0.y, n2d);
    n2d = fma((double)c0.z, (double)c0.z, n2d); n2d = fma((double)c0.w, (double)c0.w, n2d);
    n2d = fma((double)c1.x, (double)c1.x, n2d); n2d = fma((double)c1.y, (double)c1.y, n2d);
    n2d = fma((double)c1.z, (double)c1.z, n2d); n2d = fma((double)c1.w, (double)c1.w, n2d);
    n2[t] = (float)n2d;

    {
        float cf[8] = {c0.x, c0.y, c0.z, c0.w, c1.x, c1.y, c1.z, c1.w};
        us8 ah, al;
#pragma unroll
        for (int d = 0; d < 8; ++d) {
            float f = -2.0f * cf[d];
            unsigned short h = f32_to_bf16(f);
            ah[d] = h;
            al[d] = f32_to_bf16(f - bf16_to_f32(h));
        }
        float n2f = (float)n2d;
        unsigned short nh = f32_to_bf16(n2f);
        unsigned short nl = f32_to_bf16(n2f - bf16_to_f32(nh));
        us8 anh = {nh, 0, 0, 0, 0, 0, 0, 0};
        us8 anl = {nl, 0, 0, 0, 0, 0, 0, 0};
        int ntq = t >> 4, lqt = t & 15;
        *(us8*)&aLds[AOFF(ntq, 0, 0, lqt)] = ah;
        *(us8*)&aLds[AOFF(ntq, 1, 0, lqt)] = al;
        *(us8*)&aLds[AOFF(ntq, 0, 1, lqt)] = anh;
        *(us8*)&aLds[AOFF(ntq, 1, 1, lqt)] = anl;
        if (t == 0) {
            us8 z = {0, 0, 0, 0, 0, 0, 0, 0};
            *(us8*)&aLds[ZOFF] = z;
        }
    }

    // --- load weights (quad0 lanes), absmax, build B-fragments ---
    const float* wrow = weight + (size_t)o * I_DIM;
    float m = 0.f;
    us8 Bh[8], Bl[8];
    if (quad == 0) {
#pragma unroll
        for (int g = 0; g < 8; ++g) {
            int grp = wv * 128 + g * 16 + lq;
            float4 a = *(const float4*)(wrow + grp * 8);
            float4 b = *(const float4*)(wrow + grp * 8 + 4);
            float wf[8] = {a.x, a.y, a.z, a.w, b.x, b.y, b.z, b.w};
            us8 h, l;
#pragma unroll
            for (int d = 0; d < 8; ++d) {
                m = fmaxf(m, fabsf(wf[d]));
                unsigned short hh = f32_to_bf16(wf[d]);
                h[d] = hh;
                l[d] = f32_to_bf16(wf[d] - bf16_to_f32(hh));
            }
            Bh[g] = h; Bl[g] = l;
        }
    }
    // absmax: quad0 lanes hold all 128 groups of this wave; reduce within 16-lane groups
#pragma unroll
    for (int off = 1; off < 16; off <<= 1)
        m = fmaxf(m, __shfl_xor(m, off, 64));
    if (lane == 0) red[wv] = m;
    __syncthreads();   // covers cb/n2/aLds writes too
    float s = fmaxf(fmaxf(fmaxf(red[0], red[1]), fmaxf(red[2], red[3])), 1e-6f);

    if (quad == 1) {
        unsigned short sh = f32_to_bf16(s);
        unsigned short sl = f32_to_bf16(s - bf16_to_f32(sh));
        us8 vh = {sh, 0, 0, 0, 0, 0, 0, 0};
        us8 vl = {sl, 0, 0, 0, 0, 0, 0, 0};
#pragma unroll
        for (int g = 0; g < 8; ++g) { Bh[g] = vh; Bl[g] = vl; }
    } else if (quad >= 2) {
        us8 z = {0, 0, 0, 0, 0, 0, 0, 0};
#pragma unroll
        for (int g = 0; g < 8; ++g) { Bh[g] = z; Bl[g] = z; }
    }

    // --- MFMA search: 16 cw-tiles x 8 group-tiles, 4 split terms each ---
    float best[8], sec[8];
    int bi[8];
#pragma unroll
    for (int g = 0; g < 8; ++g) { best[g] = 1e30f; sec[g] = 1e30f; bi[g] = 0; }

#pragma unroll 1
    for (int nt = 0; nt < 16; ++nt) {
        int a0 = (quad < 2) ? AOFF(nt, 0, quad, lq) : ZOFF;
        int a1 = (quad < 2) ? AOFF(nt, 1, quad, lq) : ZOFF;
        bf16x8 A1 = *(const bf16x8*)&aLds[a0];
        bf16x8 A2 = *(const bf16x8*)&aLds[a1];
#pragma unroll
        for (int g = 0; g < 8; ++g) {
            f32x4 acc = {0.f, 0.f, 0.f, 0.f};
            acc = __builtin_amdgcn_mfma_f32_16x16x32_bf16(A1, __builtin_bit_cast(bf16x8, Bh[g]), acc, 0, 0, 0);
            acc = __builtin_amdgcn_mfma_f32_16x16x32_bf16(A1, __builtin_bit_cast(bf16x8, Bl[g]), acc, 0, 0, 0);
            acc = __builtin_amdgcn_mfma_f32_16x16x32_bf16(A2, __builtin_bit_cast(bf16x8, Bh[g]), acc, 0, 0, 0);
            acc = __builtin_amdgcn_mfma_f32_16x16x32_bf16(A2, __builtin_bit_cast(bf16x8, Bl[g]), acc, 0, 0, 0);
#pragma unroll
            for (int r = 0; r < 4; ++r) {
                float e = acc[r];
                int cwv = nt * 16 + quad * 4 + r;   // C row = (lane>>4)*4 + r (m89-verified)
                bool lt = e < best[g];
                sec[g] = __builtin_amdgcn_fmed3f(sec[g], best[g], e);
                best[g] = fminf(best[g], e);
                bi[g] = lt ? cwv : bi[g];
            }
        }
    }

    // --- merge across the 4 k-quads (lanes l, l^16, l^32, l^48 share a group) ---
#pragma unroll
    for (int g = 0; g < 8; ++g) {
#pragma unroll
        for (int msk = 16; msk <= 32; msk <<= 1) {
            float ob = __shfl_xor(best[g], msk, 64);
            float os = __shfl_xor(sec[g], msk, 64);
            int   oi = __shfl_xor(bi[g], msk, 64);
            bool tk = (ob < best[g]) || (ob == best[g] && oi < bi[g]);   // np.argmin: smaller index wins ties
            sec[g] = fminf(fmaxf(best[g], ob), fminf(sec[g], os));
            best[g] = tk ? ob : best[g];
            bi[g] = tk ? oi : bi[g];
        }
    }

    // --- exact fallback (rare) + dequant: quad0 lanes own the 16 groups/tile ---
    if (quad == 0) {
#pragma unroll 1
        for (int g = 0; g < 8; ++g) {
            int grp = wv * 128 + g * 16 + lq;
            if (sec[g] - best[g] < TAU) {
                float wk[8];
#pragma unroll
                for (int d = 0; d < 8; ++d) wk[d] = wrow[grp * 8 + d];
                double sd = (double)s;
                double gg[PQD];
#pragma unroll
                for (int d = 0; d < PQD; ++d) gg[d] = (double)wk[d] / sd;
                double bb = 1e300; int bbi = 0;
                float cut = best[g] + CUT;
                for (int c = 0; c < KCB; ++c) {
                    float4 p0 = *(const float4*)&cb[c * PQD];
                    float4 p1 = *(const float4*)&cb[c * PQD + 4];
                    float d0 = 0.f;
                    d0 = fmaf(p0.x, wk[0], d0); d0 = fmaf(p0.y, wk[1], d0);
                    d0 = fmaf(p0.z, wk[2], d0); d0 = fmaf(p0.w, wk[3], d0);
                    d0 = fmaf(p1.x, wk[4], d0); d0 = fmaf(p1.y, wk[5], d0);
                    d0 = fmaf(p1.z, wk[6], d0); d0 = fmaf(p1.w, wk[7], d0);
                    float e0 = fmaf(-2.f, d0, s * n2[c]);
                    if (e0 <= cut) {
                        double n = 0.0, dot = 0.0;
#pragma unroll
                        for (int d = 0; d < PQD; ++d) {
                            double cv = (double)cb[c * PQD + d];
                            n = fma(cv, cv, n);
                            dot = fma(cv, gg[d], dot);
                        }
                        double d2 = fma(-2.0, dot, n);
                        if (d2 < bb) { bb = d2; bbi = c; }
                    }
                }
                bi[g] = bbi;
            }
            // dequantize group grp
            unsigned short u[8];
#pragma unroll
            for (int d = 0; d < PQD; ++d) u[d] = f32_to_bf16(cb[bi[g] * PQD + d] * s);
            uint4 r;
            r.x = pack2(u[0], u[1]); r.y = pack2(u[2], u[3]);
            r.z = pack2(u[4], u[5]); r.w = pack2(u[6], u[7]);
            *(uint4*)(wq + (size_t)o * I_DIM + grp * 8) = r;
        }
    }
}

// ---------------- 2. 256x256 8-phase bf16 MFMA GEMM + bias (round-1 verified, 125 us) ----------------
#define GBM 256
#define GBN 256
#define NIT 32   // 32 iters x 2 K-tiles x 64 = 4096

#define LOFF_A(b,h) ((b)*32768 + (h)*8192)
#define LOFF_B(b,h) ((b)*32768 + 16384 + (h)*8192)

#define BARX() asm volatile("s_barrier" ::: "memory")
#define WAITV(n) asm volatile("s_waitcnt vmcnt(" #n ")" ::: "memory")

#define STAGE(P, h, kt, loff)                                                       \
  { _Pragma("unroll")                                                               \
    for (int l_ = 0; l_ < 2; ++l_) {                                                \
      const unsigned short* g_ = (P) + (size_t)((h) * 128 + l_ * 64) * I_DIM + (size_t)(kt) * 64; \
      unsigned short* d_ = (unsigned short*)&lds[(loff) + l_ * 4096 + wave * 512];  \
      __builtin_amdgcn_global_load_lds((const __attribute__((address_space(1))) void*)g_, \
                                       (__attribute__((address_space(3))) void*)d_, 16, 0, 0); \
    } }

#define READ_B(boff)                                                                \
  { _Pragma("unroll")                                                               \
    for (int kk_ = 0; kk_ < 2; ++kk_) {                                             \
      _Pragma("unroll")                                                             \
      for (int j_ = 0; j_ < 4; ++j_)                                                \
        bf[kk_][j_] = *(const bf16x8*)&lds[(boff) + baseB + j_ * 1024 + cxo[kk_]];  \
    } }

#define READ_A(boff, p)                                                             \
  { _Pragma("unroll")                                                               \
    for (int kk_ = 0; kk_ < 2; ++kk_) {                                             \
      _Pragma("unroll")                                                             \
      for (int ii_ = 0; ii_ < 2; ++ii_)                                             \
        af[kk_][ii_] = *(const bf16x8*)&lds[(boff) + baseA + (2 * (p) + ii_) * 1024 + cxo[kk_]]; \
    } }

#define MFMA_Q(p)                                                                   \
  { __builtin_amdgcn_s_setprio(1);                                                  \
    _Pragma("unroll")                                                               \
    for (int ii_ = 0; ii_ < 2; ++ii_) {                                             \
      _Pragma("unroll")                                                             \
      for (int j_ = 0; j_ < 4; ++j_) {                                              \
        _Pragma("unroll")                                                           \
        for (int kk_ = 0; kk_ < 2; ++kk_)                                           \
          acc[2 * (p) + ii_][j_] = __builtin_amdgcn_mfma_f32_16x16x32_bf16(         \
              af[kk_][ii_], bf[kk_][j_], acc[2 * (p) + ii_][j_], 0, 0, 0);          \
      }                                                                             \
    }                                                                               \
    __builtin_amdgcn_s_setprio(0); }

__global__ __launch_bounds__(512, 2) void gemm_8phase(const unsigned short* __restrict__ A, // [BS_TOK][I]
                                                      const unsigned short* __restrict__ B, // [O_DIM][I]
                                                      const float* __restrict__ bias,
                                                      float* __restrict__ C) {
    __shared__ __align__(16) unsigned short lds[65536];   // 128 KiB: 2 bufs x (A 256x64 + B 256x64)

    const int t = threadIdx.x;
    const int wave = t >> 6;
    const int lane = t & 63;
    const int q = lane >> 4;
    const int lr = lane & 15;
    const int wr = wave >> 2;   // 0..1 (M)
    const int wc = wave & 3;    // 0..3 (N)

    // bijective XCD swizzle: 256 wgs, XCD x owns column-panel tn=x
    const int swz = (((int)blockIdx.x & 7) * 32) + ((int)blockIdx.x >> 3);
    const int bm = (swz & 31) * GBM;
    const int bn = (swz >> 5) * GBN;

    // staging: thread t covers row (l*64 + t/8), 16B chunk (t%8); source chunk
    // pre-swizzled by ^(row&7) so LDS stays linear (rule #21)
    const int trow = t >> 3;
    const int csw = ((t & 7) ^ (trow & 7)) * 8;
    const unsigned short* pa = A + (size_t)(bm + trow) * I_DIM + csw;
    const unsigned short* pb = B + (size_t)(bn + trow) * I_DIM + csw;

    // read bases (shorts)
    const int baseA = wr * 8192 + lr * 64;
    const int baseB = 16384 + (wc >> 1) * 8192 + ((wc & 1) * 64 + lr) * 64;
    const int cxo[2] = { (q ^ (lr & 7)) * 8, ((4 + q) ^ (lr & 7)) * 8 };

    f32x4 acc[8][4] = {};
    bf16x8 bf[2][4];
    bf16x8 af[2][2];

    // ---- prologue: tile0 (buf0, 4 halves) + tile1.B (buf1) ----
    STAGE(pa, 0, 0, LOFF_A(0, 0));
    STAGE(pa, 1, 0, LOFF_A(0, 1));
    STAGE(pb, 0, 0, LOFF_B(0, 0));
    STAGE(pb, 1, 0, LOFF_B(0, 1));
    STAGE(pb, 0, 1, LOFF_B(1, 0));
    STAGE(pb, 1, 1, LOFF_B(1, 1));
    WAITV(4);          // tile0 landed; tile1.B (4 loads) stays in flight
    BARX();

#pragma unroll 1
    for (int i = 0; i < NIT; ++i) {
        const int kO  = 2 * i + 1;
        const int kN  = 2 * i + 2;
        const int kN1 = 2 * i + 3;
        const bool nl = (i < NIT - 1);

        // P0: tile E quad0 (buf0); stage O.A0 -> buf1.A0
        READ_B(0);
        READ_A(0, 0);
        STAGE(pa, 0, kO, LOFF_A(1, 0));
        BARX();
        MFMA_Q(0);
        BARX();

        // P1: quad1; stage O.A1 -> buf1.A1 ; (E+2).B0 -> buf0.B0
        READ_A(0, 1);
        STAGE(pa, 1, kO, LOFF_A(1, 1));
        if (nl) STAGE(pb, 0, kN, LOFF_B(0, 0));
        BARX();
        MFMA_Q(1);
        BARX();

        // P2: quad2; stage (E+2).B1 -> buf0.B1
        READ_A(0, 2);
        if (nl) STAGE(pb, 1, kN, LOFF_B(0, 1));
        BARX();
        MFMA_Q(2);
        BARX();

        // P3: quad3; counted wait covers tile O (A+B landed)
        READ_A(0, 3);
        BARX();
        MFMA_Q(3);
        if (nl) { WAITV(4); } else { WAITV(0); }
        BARX();

        // P4: tile O quad0 (buf1); stage (E+2).A0 -> buf0.A0
        READ_B(32768);
        READ_A(32768, 0);
        if (nl) STAGE(pa, 0, kN, LOFF_A(0, 0));
        BARX();
        MFMA_Q(0);
        BARX();

        // P5: quad1; stage (E+2).A1 -> buf0.A1
        READ_A(32768, 1);
        if (nl) STAGE(pa, 1, kN, LOFF_A(0, 1));
        BARX();
        MFMA_Q(1);
        BARX();

        // P6: quad2; stage (O+2).B0 -> buf1.B0
        READ_A(32768, 2);
        if (nl) STAGE(pb, 0, kN1, LOFF_B(1, 0));
        BARX();
        MFMA_Q(2);
        BARX();

        // P7: quad3; counted wait covers tile E+2 (buf0 complete)
        READ_A(32768, 3);
        if (nl) STAGE(pb, 1, kN1, LOFF_B(1, 1));
        BARX();
        MFMA_Q(3);
        WAITV(4);   // no-op on last iter (0 outstanding)
        BARX();
    }

    // ---- epilogue: C = acc + bias ----
#pragma unroll
    for (int ii = 0; ii < 8; ++ii) {
        const int m0 = bm + wr * 128 + ii * 16 + q * 4;
#pragma unroll
        for (int j = 0; j < 4; ++j) {
            const int n = bn + wc * 64 + j * 16 + lr;
            const float bv = bias[n];
            float* cp = C + (size_t)m0 * O_DIM + n;
#pragma unroll
            for (int r = 0; r < 4; ++r)
                cp[(size_t)r * O_DIM] = acc[ii][j][r] + bv;
        }
    }
}

extern "C" void kernel_launch(void* const* d_in, const int* in_sizes, int n_in,
                              void* d_out, int out_size, void* d_ws, size_t ws_size,
                              hipStream_t stream) {
    const float* x        = (const float*)d_in[0];
    const float* weight   = (const float*)d_in[1];
    const float* codebook = (const float*)d_in[2];
    const float* bias     = (const float*)d_in[3];
    float* out = (float*)d_out;

    char* ws = (char*)d_ws;
    unsigned short* wq = (unsigned short*)ws;                               // 16 MB
    unsigned short* xb = (unsigned short*)(ws + (size_t)O_DIM * I_DIM * 2); // 64 MB

    assign_convert_kernel<<<3072, 256, 0, stream>>>(weight, codebook, wq, x, xb);
    gemm_8phase<<<256, 512, 0, stream>>>(xb, wq, bias, out);
}